// Round 11
// baseline (138.066 us; speedup 1.0000x reference)
//
#include <hip/hip_runtime.h>
#include <hip/hip_bf16.h>
#include <math.h>

// HIR rainfall-runoff scan — tolerance-bracketed time-chunking + exact fixup.
//
// V12 = V10 (117.4 us best; pass1 43.5) with NC 16 -> 32 (CH 64 -> 32).
//  * Model (11 rounds, quantified): slot cost ~272 cy per serial step per
//    wave, CONTENT-INDEPENDENT (stepw 1-chain 275 / dstep 2-chain 272 /
//    step+Q+LDS same); co-residency free (V5: 2 waves/SIMD each at solo
//    rate); prefetch depth / load layout / store pattern all null
//    (V4/V6/V7/V8); V11 (chain-split across waves) regressed because it
//    spent the same slots for half the chains/slot. Only working lever:
//    SLOTS PER WAVE (W 384->320 = -64 slots = -5 us, measured).
//  * NC=32: slots/wave = 320 warm-up + 32 main = 352 (vs 384). Waves double
//    to 2048 = 2/SIMD — free per V5 (combined issue ~220 cy < 272 budget).
//    Exact chunks now c <= 10. Same W / MERGE_TOL / tolerance regime.
//  * LDS tile [32][65]; store phase splits the wave: lanes 0-31 rows 0-31,
//    lanes 32-63 rows 32-63 (2 lanes/bank = free). Fixup unchanged at NC=32
//    granularity.
//
// Q[b,t] (t>=1) = fluxes from carry entering step t; Q[b,0] uses the FINAL
// carry (jnp.roll wraparound) with t=0 inputs (chunk NC-1 owner writes it).

struct P {
    float INSC, SMSC, RecK, g1, lc, k1, k2, k3, c2;
    // g1=1-RecK, lc=log2(COEFF), k1=SUB/SMSC, k2=CRAK/SMSC, k3=10/SMSC,
    // c2=-SQ/SMSC*log2(e)
};

__device__ __forceinline__ P make_params(const float* pINSC, const float* pCOEFF,
                                         const float* pSQ,   const float* pSMSC,
                                         const float* pSUB,  const float* pCRAK,
                                         const float* pRecK) {
    P p;
    p.INSC      = fminf(fmaxf(pINSC[0]  * 5.0f,   0.5f),   5.0f);
    float COEFF = fminf(fmaxf(pCOEFF[0] * 400.0f, 50.0f),  400.0f);
    float SQ    = fminf(fmaxf(pSQ[0]    * 6.0f,   0.0f),   6.0f);
    p.SMSC      = fminf(fmaxf(pSMSC[0]  * 500.0f, 50.0f),  500.0f);
    float SUB   = fminf(fmaxf(pSUB[0],  0.0f), 1.0f);
    float CRAK  = fminf(fmaxf(pCRAK[0], 0.0f), 1.0f);
    p.RecK      = fminf(fmaxf(pRecK[0]  * 0.3f,   0.003f), 0.3f);
    p.g1 = 1.0f - p.RecK;
    p.lc = log2f(COEFF);
    float inv = 1.0f / p.SMSC;
    p.k1 = SUB * inv;
    p.k2 = CRAK * inv;
    p.k3 = 10.0f * inv;
    p.c2 = (-SQ * inv) * 1.44269504088896340736f;
    return p;
}

// Full step with Q. Critical sms chain: fminf -> fmaf -> exp2f -> fminf ->
// mul -> fmaf. Everything else is off-path.
__device__ __forceinline__ float step(float Prec, float PET, float& sms, float& gw, const P& p) {
    float INT  = fminf(fminf(p.INSC, PET), Prec);
    float INR  = Prec - INT;
    float POT  = PET - INT;
    float S    = fminf(sms, p.SMSC);                 // lower clamp provably slack
    float u    = fmaf(-p.k1, S, 1.0f);
    float v    = fmaf(-p.k2, S, 1.0f);
    float ETS  = fminf(POT, p.k3 * S);
    float SmE  = S - ETS;
    float e    = exp2f(fmaf(p.c2, S, p.lc));         // cap = COEFF*2^(c2*S)
    float RMO  = fminf(INR, e);
    float w    = u * RMO;                            // t2 = RMO - SRUN
    float s2   = fmaf(v, w, SmE);                    // S + SMF - ETS
    float SMF  = v * w;
    float REC  = w - SMF;
    float RECnew = REC + fmaxf(s2 - p.SMSC, 0.0f);
    float BAS  = p.RecK * gw;
    float Q    = (INR - w) + BAS;                    // IRUN + SRUN + BAS
    gw  = fmaf(p.g1, gw, RECnew);
    sms = s2;
    return Q;
}

// Warm-up / state-advance step without Q (single chain, carries gw).
__device__ __forceinline__ void stepw(float Prec, float PET, float& sms, float& gw, const P& p) {
    float INT  = fminf(fminf(p.INSC, PET), Prec);
    float INR  = Prec - INT;
    float POT  = PET - INT;
    float S    = fminf(sms, p.SMSC);
    float u    = fmaf(-p.k1, S, 1.0f);
    float v    = fmaf(-p.k2, S, 1.0f);
    float ETS  = fminf(POT, p.k3 * S);
    float SmE  = S - ETS;
    float e    = exp2f(fmaf(p.c2, S, p.lc));
    float RMO  = fminf(INR, e);
    float w    = u * RMO;
    float s2   = fmaf(v, w, SmE);
    float SMF  = v * w;
    float REC  = w - SMF;
    float RECnew = REC + fmaxf(s2 - p.SMSC, 0.0f);
    gw  = fmaf(p.g1, gw, RECnew);
    sms = s2;
}

// Dual-bracket warm-up step: hi chain carries gw; lo chain is sms-only.
// Shares INT/INR/POT between the chains; 2 chains fit in one ~272 cy slot.
__device__ __forceinline__ void dstep(float Prec, float PET,
                                      float& slo, float& shi, float& gw, const P& p) {
    float INT = fminf(fminf(p.INSC, PET), Prec);
    float INR = Prec - INT;
    float POT = PET - INT;
    {   // hi + gw
        float S    = fminf(shi, p.SMSC);
        float u    = fmaf(-p.k1, S, 1.0f);
        float v    = fmaf(-p.k2, S, 1.0f);
        float ETS  = fminf(POT, p.k3 * S);
        float SmE  = S - ETS;
        float e    = exp2f(fmaf(p.c2, S, p.lc));
        float RMO  = fminf(INR, e);
        float w    = u * RMO;
        float s2   = fmaf(v, w, SmE);
        float SMF  = v * w;
        float REC  = w - SMF;
        float RECnew = REC + fmaxf(s2 - p.SMSC, 0.0f);
        gw  = fmaf(p.g1, gw, RECnew);
        shi = s2;
    }
    {   // lo, sms only
        float S    = fminf(slo, p.SMSC);
        float u    = fmaf(-p.k1, S, 1.0f);
        float v    = fmaf(-p.k2, S, 1.0f);
        float ETS  = fminf(POT, p.k3 * S);
        float SmE  = S - ETS;
        float e    = exp2f(fmaf(p.c2, S, p.lc));
        float RMO  = fminf(INR, e);
        float w    = u * RMO;
        slo = fmaf(v, w, SmE);
    }
}

#define MERGE_TOL 0.75f

// ---------------------------------------------------------------------------
// 3-buffer, 4-float4-batch software pipeline (distance-2, no register copies).
// Ambient names: bp (const float4* batch base), B0/B1/B2 (float4[4]).
// Batch j lives in B[j%3]; the load for batch j+2 issues in batch j's slot.
// Clamped tail loads always target already-consumed buffers (any NB >= 1).
// ---------------------------------------------------------------------------

#define LB(DST, K, NB) do { int _kn = (K) < (NB) ? (K) : (NB) - 1;              \
    _Pragma("unroll") for (int _q = 0; _q < 4; ++_q) DST[_q] = bp[4 * _kn + _q]; } while (0)

#define PIPE3(NB, CB) do { if ((NB) > 0) {                                      \
    LB(B0, 0, (NB)); LB(B1, 1, (NB));                                           \
    int _j = 0;                                                                 \
    for (; _j + 3 <= (NB); _j += 3) {                                           \
        LB(B2, _j + 2, (NB)); CB(B0, _j);                                       \
        LB(B0, _j + 3, (NB)); CB(B1, _j + 1);                                   \
        LB(B1, _j + 4, (NB)); CB(B2, _j + 2);                                   \
    }                                                                           \
    if (_j < (NB)) { LB(B2, _j + 2, (NB)); CB(B0, _j); ++_j;                    \
        if (_j < (NB)) { LB(B0, _j + 2, (NB)); CB(B1, _j); } }                  \
} } while (0)

// Compute-batch macros (8 steps per batch).
#define CBW(BUF, J) do { _Pragma("unroll") for (int _m = 0; _m < 4; ++_m) {     \
    stepw(BUF[_m].x, BUF[_m].y, shi, gw, p);                                    \
    stepw(BUF[_m].z, BUF[_m].w, shi, gw, p); } } while (0)

#define CBD(BUF, J) do { _Pragma("unroll") for (int _m = 0; _m < 4; ++_m) {     \
    dstep(BUF[_m].x, BUF[_m].y, slo, shi, gw, p);                               \
    dstep(BUF[_m].z, BUF[_m].w, slo, shi, gw, p); } } while (0)

#define CBM(BUF, J) do { int _tb = 8 * (J);                                     \
    _Pragma("unroll") for (int _m = 0; _m < 4; ++_m) {                          \
    float _qa = step(BUF[_m].x, BUF[_m].y, sms, gw, p);                         \
    float _qb = step(BUF[_m].z, BUF[_m].w, sms, gw, p);                         \
    lds_q[_tb + 2 * _m][l] = _qa; lds_q[_tb + 2 * _m + 1][l] = _qb; } } while (0)

#define CBF(BUF, J) do { _Pragma("unroll") for (int _m = 0; _m < 4; ++_m) {     \
    float _qa = step(BUF[_m].x, BUF[_m].y, sms, gw, p);                         \
    float _qb = step(BUF[_m].z, BUF[_m].w, sms, gw, p);                         \
    orow2[ib0 + 4 * (J) + _m] = make_float2(_qa, _qb); } } while (0)

// ---------------------------------------------------------------------------
// Pass 1: one thread per (b, c); lanes = 64 consecutive b, c wave-uniform.
// CH=32: main chunk is 4 batches; Q buffered in LDS [32][65] and written
// back with split-lane coalesced stores.
// ---------------------------------------------------------------------------

template<int T, int NC, int W>
__global__ __launch_bounds__(64, 1)
void hir_pass1(const float* __restrict__ inputs,
               const float* __restrict__ pINSC,  const float* __restrict__ pCOEFF,
               const float* __restrict__ pSQ,    const float* __restrict__ pSMSC,
               const float* __restrict__ pSUB,   const float* __restrict__ pCRAK,
               const float* __restrict__ pRecK,
               float* __restrict__ out, float4* __restrict__ st, int B)
{
    constexpr int CH = T / NC;             // 32 steps
    __shared__ float lds_q[CH][65];        // [t_local][lane], +1 pad
    const int l   = threadIdx.x;
    const int gid = blockIdx.x * 64 + l;
    const int b = gid % B;                 // consecutive lanes -> consecutive rows
    const int c = gid / B;                 // wave-uniform (B % 64 == 0)
    if (c >= NC) return;                   // never taken for the exact grid

    P p = make_params(pINSC, pCOEFF, pSQ, pSMSC, pSUB, pCRAK, pRecK);

    const float4* __restrict__ rp = (const float4*)(inputs + (size_t)b * (2 * T));
    float* __restrict__ orow = out + (size_t)b * T;

    const int i1 = (c * CH) >> 1;          // first main float4 index
    int i0 = i1 - (W >> 1);                // warm-up start (W/2 float4s)
    const bool exact = (i0 <= 0);
    if (i0 < 0) i0 = 0;

    float slo = 0.0f, shi = exact ? 0.0f : p.SMSC, gw = 0.0f;
    float4 B0[4], B1[4], B2[4];

    // ---- Warm-up: pipelined batches (8 steps each), wave-uniform branch ----
    {
        const int nb = (i1 - i0) >> 2;     // 4c for exact (c<=10), else 40
        const float4* bp = rp + i0;
        if (exact) {
            PIPE3(nb, CBW);                // advances shi (true chain)
            slo = shi;
        } else {
            PIPE3(nb, CBD);                // dual bracket chains
        }
    }
    const bool merged = exact || ((shi - slo) <= MERGE_TOL);
    float sms = exact ? shi : (0.5f * (slo + shi));

    // ---- Main chunk: CH/8 = 4 batches, Q -> LDS (bank-conflict-free) ----
    {
        const float4* bp = rp + i1;
        PIPE3(CH / 8, CBM);
    }

    st[(size_t)c * B + b] = make_float4(sms, gw, merged ? 1.0f : 0.0f, 0.0f);

    // Q[b,0] from the final carry (jnp.roll wraparound), owned by chunk NC-1.
    float q0 = 0.0f;
    const bool hasq0 = (c == NC - 1);
    if (hasq0) {
        float4 f0 = rp[0];
        float ss = sms, gg = gw;
        q0 = step(f0.x, f0.y, ss, gg, p);
    }

    __syncthreads();                       // lds_q visible across the wave

    // ---- Store phase: split-lane coalesced columns.
    //      tl = l&31 indexes t_local; half = l>>5 selects rows 0-31 / 32-63.
    //      out[b0+half*32+j][t1+tl] = lds_q[tl][half*32+j].
    //      Each instr: two 128 B contiguous segments; LDS 2 lanes/bank. ----
    const int b0 = b - l;                  // wave base row (B % 64 == 0)
    const int t1 = c * CH;
    const int tl = l & 31;
    const int rbase = (l >> 5) << 5;       // 0 or 32
    if (c == 0) {
        if (tl > 0) {                      // t==0 owned by the wraparound
            for (int j = 0; j < 32; ++j)
                out[(size_t)(b0 + rbase + j) * T + tl] = lds_q[tl][rbase + j];
        }
    } else {
        for (int j = 0; j < 32; ++j)
            out[(size_t)(b0 + rbase + j) * T + t1 + tl] = lds_q[tl][rbase + j];
    }
    if (hasq0) orow[0] = q0;
}

// ---------------------------------------------------------------------------
// Fixup: thread per (b, c). Merged -> one coalesced st read, exit. Unmerged
// -> walk back to nearest merged predecessor m (chunk 0 is always exact =>
// merged), advance store-free through m+1..c-1, recompute chunk c exactly
// with direct out stores. Pipelined loads throughout. Same semantics as the
// sequential per-row fixup: merged states are accepted as-is.
// ---------------------------------------------------------------------------

template<int T, int NC>
__global__ __launch_bounds__(64)
void hir_fixup(const float* __restrict__ inputs,
               const float* __restrict__ pINSC,  const float* __restrict__ pCOEFF,
               const float* __restrict__ pSQ,    const float* __restrict__ pSMSC,
               const float* __restrict__ pSUB,   const float* __restrict__ pCRAK,
               const float* __restrict__ pRecK,
               float* __restrict__ out, const float4* __restrict__ st, int B)
{
    const int gid = blockIdx.x * 64 + threadIdx.x;
    const int b = gid % B;
    const int c = gid / B;
    if (c >= NC) return;

    float4 sc = st[(size_t)c * B + b];
    if (sc.z != 0.0f) return;              // merged -> nothing to fix

    P p = make_params(pINSC, pCOEFF, pSQ, pSMSC, pSUB, pCRAK, pRecK);
    constexpr int CH = T / NC;

    const float4* __restrict__ rp = (const float4*)(inputs + (size_t)b * (2 * T));
    float* __restrict__ orow = out + (size_t)b * T;
    float2* __restrict__ orow2 = (float2*)orow;

    // Walk back to nearest merged predecessor (c >= 1 here: chunk 0 merged).
    int m = c - 1;
    float4 sm = st[(size_t)m * B + b];
    while (sm.z == 0.0f) { --m; sm = st[(size_t)m * B + b]; }
    float sms = sm.x, gw = sm.y;

    float4 B0[4], B1[4], B2[4];

    // Advance state through chunks m+1..c-1 (no stores), pipelined.
    {
        const int ia = ((m + 1) * CH) >> 1;
        const int ibx = (c * CH) >> 1;
        const int nb = (ibx - ia) >> 2;    // multiple of 4 (or 0)
        const float4* bp = rp + ia;
        float& shi = sms;                  // CBW advances "shi"
        PIPE3(nb, CBW);
    }

    // Recompute chunk c exactly, with stores, pipelined.
    {
        const int ib0 = (c * CH) >> 1;     // float2 output base index
        const float4* bp = rp + ib0;
        PIPE3(CH / 8, CBF);
    }

    if (c == NC - 1) {                     // rewrite the t=0 wraparound output
        float4 f0 = rp[0];
        float ss = sms, gg = gw;
        orow[0] = step(f0.x, f0.y, ss, gg, p);
    }
}

// Fallback: monolithic sequential (odd shapes / tiny workspace).
template<int T>
__global__ __launch_bounds__(64, 1)
void hir_scan_kernel(const float* __restrict__ inputs,
                     const float* __restrict__ pINSC,  const float* __restrict__ pCOEFF,
                     const float* __restrict__ pSQ,    const float* __restrict__ pSMSC,
                     const float* __restrict__ pSUB,   const float* __restrict__ pCRAK,
                     const float* __restrict__ pRecK,
                     float* __restrict__ out, int B)
{
    int b = blockIdx.x * blockDim.x + threadIdx.x;
    if (b >= B) return;
    P p = make_params(pINSC, pCOEFF, pSQ, pSMSC, pSUB, pCRAK, pRecK);
    const float4* __restrict__ rp = (const float4*)(inputs + (size_t)b * (2 * T));
    float* __restrict__ orow = out + (size_t)b * T;
    float sms = 0.0f, gw = 0.0f;
    float4 cur = rp[0];
    const float P0 = cur.x, E0 = cur.y;
    constexpr int NI = T / 2;
    for (int i = 0; i < NI; ++i) {
        int ni = (i + 1 < NI) ? (i + 1) : i;
        float4 nxt = rp[ni];
        float qa = step(cur.x, cur.y, sms, gw, p);
        float qb = step(cur.z, cur.w, sms, gw, p);
        if (i == 0) { orow[1] = qb; }
        else        { ((float2*)orow)[i] = make_float2(qa, qb); }
        cur = nxt;
    }
    float ss = sms, gg = gw;
    orow[0] = step(P0, E0, ss, gg, p);
}

extern "C" void kernel_launch(void* const* d_in, const int* in_sizes, int n_in,
                              void* d_out, int out_size, void* d_ws, size_t ws_size,
                              hipStream_t stream) {
    (void)n_in; (void)out_size;
    constexpr int T  = 1024;
    constexpr int NC = 32;    // chunks (CH=32): 352 slots/wave, 2048 waves
    constexpr int W  = 320;   // warm-up: gap ~250*e^(-.0201*320) ~ 0.4 < 0.75
    const float* inputs = (const float*)d_in[0];
    const float* INSC   = (const float*)d_in[1];
    const float* COEFF  = (const float*)d_in[2];
    const float* SQ     = (const float*)d_in[3];
    const float* SMSC   = (const float*)d_in[4];
    const float* SUB    = (const float*)d_in[5];
    const float* CRAK   = (const float*)d_in[6];
    const float* RecK   = (const float*)d_in[7];
    float* out = (float*)d_out;

    int B = in_sizes[0] / (2 * T);            // 4096 for the reference shape
    size_t stBytes = (size_t)B * NC * sizeof(float4);   // 2 MB

    if ((B % 64) == 0 && ws_size >= stBytes) {
        float4* st = (float4*)d_ws;
        long total = (long)B * NC;            // 131072 threads = 2048 waves
        int blocks = (int)((total + 63) / 64);
        hir_pass1<T, NC, W><<<dim3(blocks), dim3(64), 0, stream>>>(
            inputs, INSC, COEFF, SQ, SMSC, SUB, CRAK, RecK, out, st, B);
        hir_fixup<T, NC><<<dim3(blocks), dim3(64), 0, stream>>>(
            inputs, INSC, COEFF, SQ, SMSC, SUB, CRAK, RecK, out, st, B);
        return;
    }

    int blocks = (B + 63) / 64;
    hir_scan_kernel<T><<<dim3(blocks), dim3(64), 0, stream>>>(
        inputs, INSC, COEFF, SQ, SMSC, SUB, CRAK, RecK, out, B);
}

// Round 12
// 117.727 us; speedup vs baseline: 1.1728x; 1.1728x over previous
//
#include <hip/hip_runtime.h>
#include <hip/hip_bf16.h>
#include <math.h>

// HIR rainfall-runoff scan — tolerance-bracketed time-chunking + exact fixup.
//
// V13 = exact revert to V10 (best measured: 117.4 us; pass1 43.5, fixup ~13,
// ~60 us fixed harness cost incl. the 268 MB workspace re-poison fill).
//
// Closed machine model (12 rounds, all axes measured):
//  * slot cost ~272 cy/serial-step/wave (scattered loads, 1 wave/SIMD),
//    ~239 coalesced (V4) — CONTENT-INDEPENDENT (1-chain stepw / 2-chain
//    dstep / step+Q+LDS all fit under it).
//  * co-residency: 2 waves/SIMD = ~1.5x aggregate slot throughput, not 2x
//    (V5 coalesced 239->157, V12 scattered 272->232 aggregate).
//  * prefetch depth null (V7/V8); store pattern null (V6); layout worth
//    <=33 cy/slot but staging overhead eats it (V4); 2-way ILP 1.47x only
//    by halving waves (V9, net loss); wave-split chains spends slots for
//    half the chains/slot (V11); NC beyond occupancy-minimal adds warm-up
//    work 1.83x (V12).
//  * => work NC*(W+CH)*B is at its constrained minimum: NC=16 (tasks =
//    B*NC/64 = 1024 waves = 1/SIMD exactly), W=320 (gap ~0.4 < 0.75 tol;
//    W=288 puts mean gap at threshold -> fixup explodes).
//
// Q[b,t] (t>=1) = fluxes from carry entering step t; Q[b,0] uses the FINAL
// carry (jnp.roll wraparound) with t=0 inputs (chunk NC-1 owner writes it).

struct P {
    float INSC, SMSC, RecK, g1, lc, k1, k2, k3, c2;
    // g1=1-RecK, lc=log2(COEFF), k1=SUB/SMSC, k2=CRAK/SMSC, k3=10/SMSC,
    // c2=-SQ/SMSC*log2(e)
};

__device__ __forceinline__ P make_params(const float* pINSC, const float* pCOEFF,
                                         const float* pSQ,   const float* pSMSC,
                                         const float* pSUB,  const float* pCRAK,
                                         const float* pRecK) {
    P p;
    p.INSC      = fminf(fmaxf(pINSC[0]  * 5.0f,   0.5f),   5.0f);
    float COEFF = fminf(fmaxf(pCOEFF[0] * 400.0f, 50.0f),  400.0f);
    float SQ    = fminf(fmaxf(pSQ[0]    * 6.0f,   0.0f),   6.0f);
    p.SMSC      = fminf(fmaxf(pSMSC[0]  * 500.0f, 50.0f),  500.0f);
    float SUB   = fminf(fmaxf(pSUB[0],  0.0f), 1.0f);
    float CRAK  = fminf(fmaxf(pCRAK[0], 0.0f), 1.0f);
    p.RecK      = fminf(fmaxf(pRecK[0]  * 0.3f,   0.003f), 0.3f);
    p.g1 = 1.0f - p.RecK;
    p.lc = log2f(COEFF);
    float inv = 1.0f / p.SMSC;
    p.k1 = SUB * inv;
    p.k2 = CRAK * inv;
    p.k3 = 10.0f * inv;
    p.c2 = (-SQ * inv) * 1.44269504088896340736f;
    return p;
}

// Full step with Q. Critical sms chain: fminf -> fmaf -> exp2f -> fminf ->
// mul -> fmaf. Everything else is off-path.
__device__ __forceinline__ float step(float Prec, float PET, float& sms, float& gw, const P& p) {
    float INT  = fminf(fminf(p.INSC, PET), Prec);
    float INR  = Prec - INT;
    float POT  = PET - INT;
    float S    = fminf(sms, p.SMSC);                 // lower clamp provably slack
    float u    = fmaf(-p.k1, S, 1.0f);
    float v    = fmaf(-p.k2, S, 1.0f);
    float ETS  = fminf(POT, p.k3 * S);
    float SmE  = S - ETS;
    float e    = exp2f(fmaf(p.c2, S, p.lc));         // cap = COEFF*2^(c2*S)
    float RMO  = fminf(INR, e);
    float w    = u * RMO;                            // t2 = RMO - SRUN
    float s2   = fmaf(v, w, SmE);                    // S + SMF - ETS
    float SMF  = v * w;
    float REC  = w - SMF;
    float RECnew = REC + fmaxf(s2 - p.SMSC, 0.0f);
    float BAS  = p.RecK * gw;
    float Q    = (INR - w) + BAS;                    // IRUN + SRUN + BAS
    gw  = fmaf(p.g1, gw, RECnew);
    sms = s2;
    return Q;
}

// Warm-up / state-advance step without Q (single chain, carries gw).
__device__ __forceinline__ void stepw(float Prec, float PET, float& sms, float& gw, const P& p) {
    float INT  = fminf(fminf(p.INSC, PET), Prec);
    float INR  = Prec - INT;
    float POT  = PET - INT;
    float S    = fminf(sms, p.SMSC);
    float u    = fmaf(-p.k1, S, 1.0f);
    float v    = fmaf(-p.k2, S, 1.0f);
    float ETS  = fminf(POT, p.k3 * S);
    float SmE  = S - ETS;
    float e    = exp2f(fmaf(p.c2, S, p.lc));
    float RMO  = fminf(INR, e);
    float w    = u * RMO;
    float s2   = fmaf(v, w, SmE);
    float SMF  = v * w;
    float REC  = w - SMF;
    float RECnew = REC + fmaxf(s2 - p.SMSC, 0.0f);
    gw  = fmaf(p.g1, gw, RECnew);
    sms = s2;
}

// Dual-bracket warm-up step: hi chain carries gw; lo chain is sms-only.
// Shares INT/INR/POT between the chains; 2 chains fit in one ~272 cy slot.
__device__ __forceinline__ void dstep(float Prec, float PET,
                                      float& slo, float& shi, float& gw, const P& p) {
    float INT = fminf(fminf(p.INSC, PET), Prec);
    float INR = Prec - INT;
    float POT = PET - INT;
    {   // hi + gw
        float S    = fminf(shi, p.SMSC);
        float u    = fmaf(-p.k1, S, 1.0f);
        float v    = fmaf(-p.k2, S, 1.0f);
        float ETS  = fminf(POT, p.k3 * S);
        float SmE  = S - ETS;
        float e    = exp2f(fmaf(p.c2, S, p.lc));
        float RMO  = fminf(INR, e);
        float w    = u * RMO;
        float s2   = fmaf(v, w, SmE);
        float SMF  = v * w;
        float REC  = w - SMF;
        float RECnew = REC + fmaxf(s2 - p.SMSC, 0.0f);
        gw  = fmaf(p.g1, gw, RECnew);
        shi = s2;
    }
    {   // lo, sms only
        float S    = fminf(slo, p.SMSC);
        float u    = fmaf(-p.k1, S, 1.0f);
        float v    = fmaf(-p.k2, S, 1.0f);
        float ETS  = fminf(POT, p.k3 * S);
        float SmE  = S - ETS;
        float e    = exp2f(fmaf(p.c2, S, p.lc));
        float RMO  = fminf(INR, e);
        float w    = u * RMO;
        slo = fmaf(v, w, SmE);
    }
}

#define MERGE_TOL 0.75f

// ---------------------------------------------------------------------------
// 3-buffer, 4-float4-batch software pipeline (distance-2, no register copies).
// Ambient names: bp (const float4* batch base), B0/B1/B2 (float4[4]).
// Batch j lives in B[j%3]; the load for batch j+2 issues in batch j's slot.
// Clamped tail loads always target already-consumed buffers.
// ---------------------------------------------------------------------------

#define LB(DST, K, NB) do { int _kn = (K) < (NB) ? (K) : (NB) - 1;              \
    _Pragma("unroll") for (int _q = 0; _q < 4; ++_q) DST[_q] = bp[4 * _kn + _q]; } while (0)

#define PIPE3(NB, CB) do { if ((NB) > 0) {                                      \
    LB(B0, 0, (NB)); LB(B1, 1, (NB));                                           \
    int _j = 0;                                                                 \
    for (; _j + 3 <= (NB); _j += 3) {                                           \
        LB(B2, _j + 2, (NB)); CB(B0, _j);                                       \
        LB(B0, _j + 3, (NB)); CB(B1, _j + 1);                                   \
        LB(B1, _j + 4, (NB)); CB(B2, _j + 2);                                   \
    }                                                                           \
    if (_j < (NB)) { LB(B2, _j + 2, (NB)); CB(B0, _j); ++_j;                    \
        if (_j < (NB)) { LB(B0, _j + 2, (NB)); CB(B1, _j); } }                  \
} } while (0)

// Compute-batch macros (8 steps per batch).
#define CBW(BUF, J) do { _Pragma("unroll") for (int _m = 0; _m < 4; ++_m) {     \
    stepw(BUF[_m].x, BUF[_m].y, shi, gw, p);                                    \
    stepw(BUF[_m].z, BUF[_m].w, shi, gw, p); } } while (0)

#define CBD(BUF, J) do { _Pragma("unroll") for (int _m = 0; _m < 4; ++_m) {     \
    dstep(BUF[_m].x, BUF[_m].y, slo, shi, gw, p);                               \
    dstep(BUF[_m].z, BUF[_m].w, slo, shi, gw, p); } } while (0)

#define CBM(BUF, J) do { int _tb = 8 * (J);                                     \
    _Pragma("unroll") for (int _m = 0; _m < 4; ++_m) {                          \
    float _qa = step(BUF[_m].x, BUF[_m].y, sms, gw, p);                         \
    float _qb = step(BUF[_m].z, BUF[_m].w, sms, gw, p);                         \
    lds_q[_tb + 2 * _m][l] = _qa; lds_q[_tb + 2 * _m + 1][l] = _qb; } } while (0)

#define CBF(BUF, J) do { _Pragma("unroll") for (int _m = 0; _m < 4; ++_m) {     \
    float _qa = step(BUF[_m].x, BUF[_m].y, sms, gw, p);                         \
    float _qb = step(BUF[_m].z, BUF[_m].w, sms, gw, p);                         \
    orow2[ib0 + 4 * (J) + _m] = make_float2(_qa, _qb); } } while (0)

// ---------------------------------------------------------------------------
// Pass 1: one thread per (b, c); lanes = 64 consecutive b, c wave-uniform.
// Q buffered in LDS and written coalesced (store-transpose).
// ---------------------------------------------------------------------------

template<int T, int NC, int W>
__global__ __launch_bounds__(64, 1)
void hir_pass1(const float* __restrict__ inputs,
               const float* __restrict__ pINSC,  const float* __restrict__ pCOEFF,
               const float* __restrict__ pSQ,    const float* __restrict__ pSMSC,
               const float* __restrict__ pSUB,   const float* __restrict__ pCRAK,
               const float* __restrict__ pRecK,
               float* __restrict__ out, float4* __restrict__ st, int B)
{
    __shared__ float lds_q[64][65];        // [t_local][lane], +1 pad: bank-free
    const int l   = threadIdx.x;
    const int gid = blockIdx.x * 64 + l;
    const int b = gid % B;                 // consecutive lanes -> consecutive rows
    const int c = gid / B;                 // wave-uniform (B % 64 == 0)
    if (c >= NC) return;                   // never taken for the exact grid

    P p = make_params(pINSC, pCOEFF, pSQ, pSMSC, pSUB, pCRAK, pRecK);

    const float4* __restrict__ rp = (const float4*)(inputs + (size_t)b * (2 * T));
    float* __restrict__ orow = out + (size_t)b * T;

    constexpr int CH = T / NC;             // 64 steps
    const int i1 = (c * CH) >> 1;          // first main float4 index
    int i0 = i1 - (W >> 1);                // warm-up start (W/2 float4s)
    const bool exact = (i0 <= 0);
    if (i0 < 0) i0 = 0;

    float slo = 0.0f, shi = exact ? 0.0f : p.SMSC, gw = 0.0f;
    float4 B0[4], B1[4], B2[4];

    // ---- Warm-up: pipelined batches (8 steps each), wave-uniform branch ----
    {
        const int nb = (i1 - i0) >> 2;     // in {0, 8, 16, 24, 32, 40}
        const float4* bp = rp + i0;
        if (exact) {
            PIPE3(nb, CBW);                // advances shi (true chain)
            slo = shi;
        } else {
            PIPE3(nb, CBD);                // dual bracket chains
        }
    }
    const bool merged = exact || ((shi - slo) <= MERGE_TOL);
    float sms = exact ? shi : (0.5f * (slo + shi));

    // ---- Main chunk: 8 batches, Q -> LDS (bank-conflict-free) ----
    {
        const float4* bp = rp + i1;
        PIPE3(8, CBM);
    }

    st[(size_t)c * B + b] = make_float4(sms, gw, merged ? 1.0f : 0.0f, 0.0f);

    // Q[b,0] from the final carry (jnp.roll wraparound), owned by chunk NC-1.
    float q0 = 0.0f;
    const bool hasq0 = (c == NC - 1);
    if (hasq0) {
        float4 f0 = rp[0];
        float ss = sms, gg = gw;
        q0 = step(f0.x, f0.y, ss, gg, p);
    }

    __syncthreads();                       // lds_q visible across the wave

    // ---- Store phase: coalesced columns. out[b0+j][t1+l] = lds_q[l][j] ----
    const int b0 = b - l;                  // wave base row (B % 64 == 0)
    const int t1 = c * CH;
    if (c == 0) {
        if (l > 0) {                       // lane 0 would write t=0 (owned by roll)
            for (int j = 0; j < 64; ++j)
                out[(size_t)(b0 + j) * T + l] = lds_q[l][j];
        }
    } else {
        for (int j = 0; j < 64; ++j)
            out[(size_t)(b0 + j) * T + t1 + l] = lds_q[l][j];
    }
    if (hasq0) orow[0] = q0;
}

// ---------------------------------------------------------------------------
// Fixup: thread per (b, c). Merged -> one coalesced st read, exit. Unmerged
// -> walk back to nearest merged predecessor m (chunk 0 is always exact =>
// merged), advance store-free through m+1..c-1, recompute chunk c exactly
// with direct out stores. Pipelined loads throughout. Same semantics as the
// sequential per-row fixup: merged states are accepted as-is.
// ---------------------------------------------------------------------------

template<int T, int NC>
__global__ __launch_bounds__(64)
void hir_fixup(const float* __restrict__ inputs,
               const float* __restrict__ pINSC,  const float* __restrict__ pCOEFF,
               const float* __restrict__ pSQ,    const float* __restrict__ pSMSC,
               const float* __restrict__ pSUB,   const float* __restrict__ pCRAK,
               const float* __restrict__ pRecK,
               float* __restrict__ out, const float4* __restrict__ st, int B)
{
    const int gid = blockIdx.x * 64 + threadIdx.x;
    const int b = gid % B;
    const int c = gid / B;
    if (c >= NC) return;

    float4 sc = st[(size_t)c * B + b];
    if (sc.z != 0.0f) return;              // merged -> nothing to fix

    P p = make_params(pINSC, pCOEFF, pSQ, pSMSC, pSUB, pCRAK, pRecK);
    constexpr int CH = T / NC;

    const float4* __restrict__ rp = (const float4*)(inputs + (size_t)b * (2 * T));
    float* __restrict__ orow = out + (size_t)b * T;
    float2* __restrict__ orow2 = (float2*)orow;

    // Walk back to nearest merged predecessor (c >= 1 here: chunk 0 merged).
    int m = c - 1;
    float4 sm = st[(size_t)m * B + b];
    while (sm.z == 0.0f) { --m; sm = st[(size_t)m * B + b]; }
    float sms = sm.x, gw = sm.y;

    float4 B0[4], B1[4], B2[4];

    // Advance state through chunks m+1..c-1 (no stores), pipelined.
    {
        const int ia = ((m + 1) * CH) >> 1;
        const int ibx = (c * CH) >> 1;
        const int nb = (ibx - ia) >> 2;    // multiple of 8 (or 0)
        const float4* bp = rp + ia;
        float& shi = sms;                  // CBW advances "shi"
        PIPE3(nb, CBW);
    }

    // Recompute chunk c exactly, with stores, pipelined.
    {
        const int ib0 = (c * CH) >> 1;     // float2 output base index
        const float4* bp = rp + ib0;
        PIPE3(8, CBF);
    }

    if (c == NC - 1) {                     // rewrite the t=0 wraparound output
        float4 f0 = rp[0];
        float ss = sms, gg = gw;
        orow[0] = step(f0.x, f0.y, ss, gg, p);
    }
}

// Fallback: monolithic sequential (odd shapes / tiny workspace).
template<int T>
__global__ __launch_bounds__(64, 1)
void hir_scan_kernel(const float* __restrict__ inputs,
                     const float* __restrict__ pINSC,  const float* __restrict__ pCOEFF,
                     const float* __restrict__ pSQ,    const float* __restrict__ pSMSC,
                     const float* __restrict__ pSUB,   const float* __restrict__ pCRAK,
                     const float* __restrict__ pRecK,
                     float* __restrict__ out, int B)
{
    int b = blockIdx.x * blockDim.x + threadIdx.x;
    if (b >= B) return;
    P p = make_params(pINSC, pCOEFF, pSQ, pSMSC, pSUB, pCRAK, pRecK);
    const float4* __restrict__ rp = (const float4*)(inputs + (size_t)b * (2 * T));
    float* __restrict__ orow = out + (size_t)b * T;
    float sms = 0.0f, gw = 0.0f;
    float4 cur = rp[0];
    const float P0 = cur.x, E0 = cur.y;
    constexpr int NI = T / 2;
    for (int i = 0; i < NI; ++i) {
        int ni = (i + 1 < NI) ? (i + 1) : i;
        float4 nxt = rp[ni];
        float qa = step(cur.x, cur.y, sms, gw, p);
        float qb = step(cur.z, cur.w, sms, gw, p);
        if (i == 0) { orow[1] = qb; }
        else        { ((float2*)orow)[i] = make_float2(qa, qb); }
        cur = nxt;
    }
    float ss = sms, gg = gw;
    orow[0] = step(P0, E0, ss, gg, p);
}

extern "C" void kernel_launch(void* const* d_in, const int* in_sizes, int n_in,
                              void* d_out, int out_size, void* d_ws, size_t ws_size,
                              hipStream_t stream) {
    (void)n_in; (void)out_size;
    constexpr int T  = 1024;
    constexpr int NC = 16;    // chunks (CH=64): tasks = B*NC/64 = 1024 waves
    constexpr int W  = 320;   // warm-up: gap ~250*e^(-.0201*320) ~ 0.4 < 0.75
    const float* inputs = (const float*)d_in[0];
    const float* INSC   = (const float*)d_in[1];
    const float* COEFF  = (const float*)d_in[2];
    const float* SQ     = (const float*)d_in[3];
    const float* SMSC   = (const float*)d_in[4];
    const float* SUB    = (const float*)d_in[5];
    const float* CRAK   = (const float*)d_in[6];
    const float* RecK   = (const float*)d_in[7];
    float* out = (float*)d_out;

    int B = in_sizes[0] / (2 * T);            // 4096 for the reference shape
    size_t stBytes = (size_t)B * NC * sizeof(float4);   // 1 MB

    if ((B % 64) == 0 && ws_size >= stBytes) {
        float4* st = (float4*)d_ws;
        long total = (long)B * NC;            // 65536 threads = 1024 waves
        int blocks = (int)((total + 63) / 64);
        hir_pass1<T, NC, W><<<dim3(blocks), dim3(64), 0, stream>>>(
            inputs, INSC, COEFF, SQ, SMSC, SUB, CRAK, RecK, out, st, B);
        hir_fixup<T, NC><<<dim3(blocks), dim3(64), 0, stream>>>(
            inputs, INSC, COEFF, SQ, SMSC, SUB, CRAK, RecK, out, st, B);
        return;
    }

    int blocks = (B + 63) / 64;
    hir_scan_kernel<T><<<dim3(blocks), dim3(64), 0, stream>>>(
        inputs, INSC, COEFF, SQ, SMSC, SUB, CRAK, RecK, out, B);
}